// Round 12
// baseline (100.498 us; speedup 1.0000x reference)
//
#include <hip/hip_runtime.h>

typedef float fx4 __attribute__((ext_vector_type(4)));
typedef short s16x8 __attribute__((ext_vector_type(8)));
typedef __bf16 bfx8 __attribute__((ext_vector_type(8)));

#define KN 1024
#define TT 16384
#define NOUT 16382
#define NKT 32   // K' = 2048, tiles of 64

// ws layout: Bpk (64 MiB) at 0; Apk (4 MiB); B1 bitmasks (128 KiB)
#define APK_OFF 67108864u
#define B1_OFF  (APK_OFF + 4194304u)

__device__ __forceinline__ unsigned short f2bf(float f) {
  return __builtin_bit_cast(unsigned short, (__bf16)f);
}

__device__ __forceinline__ void gll16(const void* g, void* l) {
  __builtin_amdgcn_global_load_lds(
      (const __attribute__((address_space(1))) void*)g,
      (__attribute__((address_space(3))) void*)l, 16, 0, 0);
}

// ---- kernel 1: adjacency bitmask rows (1024 bits = 32 u32 per node) ----
__global__ __launch_bounds__(256) void k_masks(const float* __restrict__ A,
                                               unsigned* __restrict__ B1) {
  int k = blockIdx.x;
  int tid = threadIdx.x;
  int wv = tid >> 6, lane = tid & 63;
  for (int i = 0; i < 4; ++i) {
    int n = i * 256 + wv * 64 + lane;
    bool bit = (A[(size_t)k * KN + n] > 0.5f) && (n != k);
    unsigned long long m = __ballot(bit);
    if (lane == 0) {
      B1[k * 32 + i * 8 + wv * 2]     = (unsigned)m;
      B1[k * 32 + i * 8 + wv * 2 + 1] = (unsigned)(m >> 32);
    }
  }
}

// ---- kernel 2 (fused): blocks 0-1023 build Wc; blocks 1024+ pack X2 ----
// 128-row (A) / 128-col (B) stripe layouts for the 128x128-tile GEMM.
// Wc idx = ((((mb*32+kt)*2+qk)*4+kb)*128 + rloc)*8 + ii, mb = k>>7, rloc = k&127
// Bpk G  = ((((jb*32+kt)*2+qk)*4+kb)*128 + col), col 0..127, jb 0..127
__global__ __launch_bounds__(256) void k_wp(const unsigned* __restrict__ B1,
                                            const float* __restrict__ alpha,
                                            const float* __restrict__ beta0,
                                            const float* __restrict__ beta1,
                                            const float* __restrict__ X,
                                            unsigned short* __restrict__ Wc,
                                            unsigned short* __restrict__ Bpk) {
  int tid = threadIdx.x;
  if (blockIdx.x >= 1024) {
    // ---------------- pack path ----------------
    int G = (blockIdx.x - 1024) * 256 + tid;   // 0 .. 4,194,303
    int col = G & 127;
    int kb  = (G >> 7) & 3;
    int qk  = (G >> 9) & 1;
    int kt  = (G >> 10) & 31;
    int jb  = G >> 15;                         // 0..127
    int j   = jb * 128 + col;
    int mbase = kt * 32 + qk * 16 + kb * 4;
    unsigned v[4];
#pragma unroll
    for (int p = 0; p < 4; ++p) {
      int m = mbase + p;
      int j1 = j + 1;
      float f0 = (j1 < TT) ? X[(size_t)m * TT + j1] : 0.0f;  // s=0
      float f1 = X[(size_t)m * TT + j];                      // s=1
      v[p] = (unsigned)f2bf(f0) | ((unsigned)f2bf(f1) << 16);
    }
    uint4 w; w.x = v[0]; w.y = v[1]; w.z = v[2]; w.w = v[3];
    *reinterpret_cast<uint4*>(Bpk + (size_t)G * 8) = w;
    return;
  }
  // ---------------- weights path ----------------
  __shared__ unsigned reach[32];
  __shared__ unsigned ex2[32];
  __shared__ unsigned short list[1056];
  __shared__ int nl;
  int k = blockIdx.x;
  if (tid == 0) nl = 0;
  if (tid < 32) {
    unsigned r = B1[k * 32 + tid];
    if (tid == (k >> 5)) r |= 1u << (k & 31);  // reach = {k} | N(k)
    reach[tid] = r;
    ex2[tid] = 0;
  }
  __syncthreads();
  for (int m = tid; m < KN; m += 256)
    if ((reach[m >> 5] >> (m & 31)) & 1) {
      int i = atomicAdd(&nl, 1);
      list[i] = (unsigned short)m;
    }
  __syncthreads();
  int n2 = nl;
  for (int i = 0; i < n2; ++i) {
    int m = list[i];
    if (tid < 32) ex2[tid] |= B1[m * 32 + tid];   // union of N(m), m in reach
  }
  __syncthreads();
  if (tid < 32) ex2[tid] &= ~reach[tid];          // distance exactly 2
  __syncthreads();
  int d1 = 0, d2 = 0;
  for (int w = 0; w < 32; ++w) { d1 += __popc(reach[w]); d2 += __popc(ex2[w]); }
  d1 -= 1;  // remove self bit
  float rd1 = 1.0f / fmaxf((float)d1, 1.0f);
  float rd2 = 1.0f / fmaxf((float)d2, 1.0f);
  float c00 = beta0[0] * rd1, c01 = beta0[1] * rd1;
  float c10 = beta1[0] * rd2, c11 = beta1[1] * rd2;
  float a0 = alpha[0], a1 = alpha[1];
  int mb = k >> 7, rloc = k & 127;
  for (int q = 0; q < 4; ++q) {
    int n = tid * 4 + q;
    bool in1 = (((reach[n >> 5] >> (n & 31)) & 1) != 0) && (n != k);
    bool in2 = ((ex2[n >> 5] >> (n & 31)) & 1) != 0;
    float v0 = (in1 ? c00 : 0.f) + (in2 ? c10 : 0.f) + (n == k ? a0 : 0.f);
    float v1 = (in1 ? c01 : 0.f) + (in2 ? c11 : 0.f) + (n == k ? a1 : 0.f);
    int kt = n >> 5, qk = (n >> 4) & 1, kb = (n >> 2) & 3, ii = (n & 3) * 2;
    size_t idx = ((((size_t)(mb * 32 + kt) * 2 + qk) * 4 + kb) * 128 + rloc) * 8 + ii;
    unsigned pair = (unsigned)f2bf(v0) | ((unsigned)f2bf(v1) << 16);
    *reinterpret_cast<unsigned*>(Wc + idx) = pair;
  }
}

// ---- kernel 3: 128x128-tile GEMM, 2 blocks/CU (cross-block pipe overlap) ----
// 256 thr, 4 waves (2x2), wave tile 64x64, BK=64, LDS 64 KiB, 2 phases/K-tile.
// Stage h1(t+1) in p0, h0(t+2) in p1; vmcnt(4)+barrier per phase (R6 ladder).
__global__ __launch_bounds__(256, 2) void k_gemm(const char* __restrict__ Apk,
                                                 const char* __restrict__ Bpk,
                                                 float* __restrict__ Y) {
  __shared__ char lds[65536];  // 2 buf x { A 16K (h0|h1) | B 16K (h0|h1) }
  int bid = blockIdx.x;
  int swz = (bid & 7) * 128 + (bid >> 3);  // XCD-contiguous (1024 % 8 == 0)
  int jb = swz >> 3, mb = swz & 7;         // jb 0..127, mb 0..7
  int tid = threadIdx.x;
  int lane = tid & 63, wv = tid >> 6;
  int wm = wv >> 1, wn = wv & 1;           // wave tile: rows wm*64, cols wn*64
  int kb = lane >> 4, ml = lane & 15;
  const char* Asrc = Apk + (size_t)mb * (NKT * 2 * 8192);
  const char* Bsrc = Bpk + (size_t)jb * (NKT * 2 * 8192);

  fx4 acc[4][4];
#pragma unroll
  for (int a = 0; a < 4; ++a)
#pragma unroll
    for (int b = 0; b < 4; ++b) acc[a][b] = (fx4){0.f, 0.f, 0.f, 0.f};

  // stage one qk-half (A+B) of tile: 4 gll16 (2 A + 2 B)
  auto stage_half = [&](int tile, int h) {
    char* dst = lds + (tile & 1) * 32768 + h * 8192;
    const char* srcA = Asrc + ((size_t)(tile & (NKT - 1)) * 2 + h) * 8192;
    const char* srcB = Bsrc + ((size_t)(tile & (NKT - 1)) * 2 + h) * 8192;
    gll16(srcA + tid * 16, dst + tid * 16);
    gll16(srcA + tid * 16 + 4096, dst + tid * 16 + 4096);
    gll16(srcB + tid * 16, dst + 16384 + tid * 16);
    gll16(srcB + tid * 16 + 4096, dst + 16384 + tid * 16 + 4096);
  };

#define READ_A(dst, t, qk)                                                          \
  do {                                                                              \
    const char* Ah_ = lds + ((t) & 1) * 32768 + (qk) * 8192;                        \
    _Pragma("unroll") for (int mf = 0; mf < 4; ++mf)                                \
      dst[mf] = *(const s16x8*)(Ah_ +                                               \
          (size_t)(kb * 128 + wm * 64 + mf * 16 + ml) * 16);                        \
  } while (0)
#define READ_B(dst, t, qk)                                                          \
  do {                                                                              \
    const char* Bh_ = lds + ((t) & 1) * 32768 + 16384 + (qk) * 8192;                \
    _Pragma("unroll") for (int nf = 0; nf < 4; ++nf)                                \
      dst[nf] = *(const s16x8*)(Bh_ +                                               \
          (size_t)(kb * 128 + wn * 64 + nf * 16 + ml) * 16);                        \
  } while (0)
#define MFMA16(a_, b_)                                                              \
  do {                                                                              \
    _Pragma("unroll") for (int mf = 0; mf < 4; ++mf)                                \
      _Pragma("unroll") for (int nf = 0; nf < 4; ++nf)                              \
        acc[mf][nf] = __builtin_amdgcn_mfma_f32_16x16x32_bf16(                      \
            __builtin_bit_cast(bfx8, a_[mf]), __builtin_bit_cast(bfx8, b_[nf]),     \
            acc[mf][nf], 0, 0, 0);                                                  \
  } while (0)

  s16x8 aC[4], aN[4], bC[4], bN[4];

  // prologue: h0(0), h1(0), h0(1) = 12 gll16; vmcnt(4) drains tile-0 halves
  stage_half(0, 0); stage_half(0, 1); stage_half(1, 0);
  asm volatile("s_waitcnt vmcnt(4)" ::: "memory");
  __builtin_amdgcn_s_barrier();
  READ_A(aC, 0, 0);
  READ_B(bC, 0, 0);

  for (int kt = 0; kt < NKT; ++kt) {
    // p0: MFMA(qk0); prefetch frags(t,qk1); stage h1(t+1)
    READ_A(aN, kt, 1);
    READ_B(bN, kt, 1);
    stage_half(kt + 1, 1);
    MFMA16(aC, bC);
    asm volatile("s_waitcnt vmcnt(4)" ::: "memory");  // drains h0(kt+1)
    __builtin_amdgcn_s_barrier();
    // p1: MFMA(qk1); prefetch frags(t+1,qk0); stage h0(t+2)
    READ_A(aC, kt + 1, 0);
    READ_B(bC, kt + 1, 0);
    stage_half(kt + 2, 0);
    MFMA16(aN, bN);
    asm volatile("s_waitcnt vmcnt(4)" ::: "memory");  // drains h1(kt+1)
    __builtin_amdgcn_s_barrier();
  }
  asm volatile("s_waitcnt vmcnt(0)" ::: "memory");

  // epilogue: C/D layout col=lane&15, row=(lane>>4)*4+r
  int c0 = jb * 128 + wn * 64;
  int r0 = mb * 128 + wm * 64;
#pragma unroll
  for (int mf = 0; mf < 4; ++mf)
#pragma unroll
    for (int nf = 0; nf < 4; ++nf) {
      int c = c0 + nf * 16 + ml;
      if (c < NOUT) {
        int r = r0 + mf * 16 + (lane >> 4) * 4;
#pragma unroll
        for (int i = 0; i < 4; ++i)
          Y[(size_t)(r + i) * NOUT + c] = acc[mf][nf][i];
      }
    }
#undef READ_A
#undef READ_B
#undef MFMA16
}

extern "C" void kernel_launch(void* const* d_in, const int* in_sizes, int n_in,
                              void* d_out, int out_size, void* d_ws, size_t ws_size,
                              hipStream_t stream) {
  const float* X     = (const float*)d_in[0];
  const float* A     = (const float*)d_in[1];
  const float* alpha = (const float*)d_in[2];
  const float* beta0 = (const float*)d_in[3];
  const float* beta1 = (const float*)d_in[4];
  float* Y = (float*)d_out;
  char* ws = (char*)d_ws;
  char* Bpk = ws;                       // 64 MiB
  char* Apk = ws + APK_OFF;             // 4 MiB
  unsigned* B1 = (unsigned*)(ws + B1_OFF);

  k_masks<<<dim3(1024), dim3(256), 0, stream>>>(A, B1);
  k_wp<<<dim3(17408), dim3(256), 0, stream>>>(B1, alpha, beta0, beta1, X,
                                              (unsigned short*)Apk,
                                              (unsigned short*)Bpk);
  k_gemm<<<dim3(1024), dim3(256), 0, stream>>>(Apk, Bpk, Y);
}

// Round 13
// 92.787 us; speedup vs baseline: 1.0831x; 1.0831x over previous
//
#include <hip/hip_runtime.h>

typedef float fx4 __attribute__((ext_vector_type(4)));
typedef short s16x8 __attribute__((ext_vector_type(8)));
typedef __bf16 bfx8 __attribute__((ext_vector_type(8)));

#define KN 1024
#define TT 16384
#define NOUT 16382
#define NKT 32      // 32 m-tiles of 32 rows (64 k' each, s-major)
#define COLP 16640  // padded X^T cols (16384 + 256)
#define HLDS 49664  // per-buffer LDS: A 32768 + B 16896

// ws: Xbf (34,078,720 B) at 0; Apk (4 MiB); B1 bitmasks
#define APK_OFF 34078720u
#define B1_OFF  (APK_OFF + 4194304u)

__device__ __forceinline__ unsigned short f2bf(float f) {
  return __builtin_bit_cast(unsigned short, (__bf16)f);
}

__device__ __forceinline__ void gll16(const void* g, void* l) {
  __builtin_amdgcn_global_load_lds(
      (const __attribute__((address_space(1))) void*)g,
      (__attribute__((address_space(3))) void*)l, 16, 0, 0);
}

// ---- kernel 1: adjacency bitmask rows ----
__global__ __launch_bounds__(256) void k_masks(const float* __restrict__ A,
                                               unsigned* __restrict__ B1) {
  int k = blockIdx.x;
  int tid = threadIdx.x;
  int wv = tid >> 6, lane = tid & 63;
  for (int i = 0; i < 4; ++i) {
    int n = i * 256 + wv * 64 + lane;
    bool bit = (A[(size_t)k * KN + n] > 0.5f) && (n != k);
    unsigned long long m = __ballot(bit);
    if (lane == 0) {
      B1[k * 32 + i * 8 + wv * 2]     = (unsigned)m;
      B1[k * 32 + i * 8 + wv * 2 + 1] = (unsigned)(m >> 32);
    }
  }
}

// ---- kernel 2 (fused): blocks 0-1023 build Wc (s-major); 1024+ pack X^T bf16 ----
// Wc u16 idx = mb*524288 + (((t*2+s)*4+kb)*256 + rloc)*8 + ii   (k' = s*1024 + t*32+kb*8+ii)
// Xbf unit (o, c): 16 B = 8 bf16 = X[o*8+i, c] (0 for c >= 16384), o octet 0..127, c 0..16639
__global__ __launch_bounds__(256) void k_wp(const unsigned* __restrict__ B1,
                                            const float* __restrict__ alpha,
                                            const float* __restrict__ beta0,
                                            const float* __restrict__ beta1,
                                            const float* __restrict__ X,
                                            unsigned short* __restrict__ Wc,
                                            unsigned short* __restrict__ Xbf) {
  int tid = threadIdx.x;
  if (blockIdx.x >= 1024) {
    // ---------------- pack path: plain bf16 X^T, octet-major ----------------
    int p = blockIdx.x - 1024;       // 0..8319
    int o = p & 127;                 // m-octet
    int cb = p >> 7;                 // 0..64
    int c = cb * 256 + tid;          // 0..16639
    unsigned v[4];
#pragma unroll
    for (int q = 0; q < 4; ++q) {
      float f0 = 0.f, f1 = 0.f;
      if (c < TT) {
        f0 = X[(size_t)(o * 8 + q * 2) * TT + c];
        f1 = X[(size_t)(o * 8 + q * 2 + 1) * TT + c];
      }
      v[q] = (unsigned)f2bf(f0) | ((unsigned)f2bf(f1) << 16);
    }
    uint4 w; w.x = v[0]; w.y = v[1]; w.z = v[2]; w.w = v[3];
    *reinterpret_cast<uint4*>(Xbf + ((size_t)o * COLP + c) * 8) = w;
    return;
  }
  // ---------------- weights path ----------------
  __shared__ unsigned reach[32];
  __shared__ unsigned ex2[32];
  __shared__ unsigned short list[1056];
  __shared__ int nl;
  int k = blockIdx.x;
  if (tid == 0) nl = 0;
  if (tid < 32) {
    unsigned r = B1[k * 32 + tid];
    if (tid == (k >> 5)) r |= 1u << (k & 31);  // reach = {k} | N(k)
    reach[tid] = r;
    ex2[tid] = 0;
  }
  __syncthreads();
  for (int m = tid; m < KN; m += 256)
    if ((reach[m >> 5] >> (m & 31)) & 1) {
      int i = atomicAdd(&nl, 1);
      list[i] = (unsigned short)m;
    }
  __syncthreads();
  int n2 = nl;
  for (int i = 0; i < n2; ++i) {
    int m = list[i];
    if (tid < 32) ex2[tid] |= B1[m * 32 + tid];
  }
  __syncthreads();
  if (tid < 32) ex2[tid] &= ~reach[tid];          // distance exactly 2
  __syncthreads();
  int d1 = 0, d2 = 0;
  for (int w = 0; w < 32; ++w) { d1 += __popc(reach[w]); d2 += __popc(ex2[w]); }
  d1 -= 1;
  float rd1 = 1.0f / fmaxf((float)d1, 1.0f);
  float rd2 = 1.0f / fmaxf((float)d2, 1.0f);
  float c00 = beta0[0] * rd1, c01 = beta0[1] * rd1;
  float c10 = beta1[0] * rd2, c11 = beta1[1] * rd2;
  float a0 = alpha[0], a1 = alpha[1];
  int mb = k >> 8, rloc = k & 255;
  for (int q = 0; q < 4; ++q) {
    int n = tid * 4 + q;
    bool in1 = (((reach[n >> 5] >> (n & 31)) & 1) != 0) && (n != k);
    bool in2 = ((ex2[n >> 5] >> (n & 31)) & 1) != 0;
    float v0 = (in1 ? c00 : 0.f) + (in2 ? c10 : 0.f) + (n == k ? a0 : 0.f);
    float v1 = (in1 ? c01 : 0.f) + (in2 ? c11 : 0.f) + (n == k ? a1 : 0.f);
    int t = n >> 5, kb2 = (n >> 3) & 3, ii = n & 7;
    size_t base = (size_t)mb * 524288 +
                  ((((size_t)t * 2) * 4 + kb2) * 256 + rloc) * 8 + ii;
    Wc[base] = f2bf(v0);            // s = 0 (pairs with X[., j+1])
    Wc[base + 8192] = f2bf(v1);     // s = 1 (pairs with X[., j])
  }
}

// ---- kernel 3: 256x256 GEMM, s-major shared-B, 3-buffer depth-2 pipeline ----
// Per tile (32 m-rows = 64 k'): B staged ONCE (257 cols); s=0 frags read at
// col+1 (+16 B), s=1 at col. Stage tile t+2 during t; vmcnt(6)+lgkm+barrier/tile.
__global__ __launch_bounds__(512, 2) void k_gemm(const char* __restrict__ Apk,
                                                 const char* __restrict__ Xbf,
                                                 float* __restrict__ Y) {
  __shared__ __align__(16) char lds[3 * HLDS];  // 3 x { A(s0|s1) 32K | B 16.9K }
  int bid = blockIdx.x;
  int swz = (bid & 7) * 32 + (bid >> 3);   // XCD-contiguous work chunks
  int jb = swz >> 2, mb = swz & 3;
  int tid = threadIdx.x;
  int lane = tid & 63, wv = tid >> 6;
  int wm = wv >> 2, wn = wv & 3;           // wave out: rows wm*128, cols wn*64
  int kb = lane >> 4, ml = lane & 15;
  const char* Asrc = Apk + (size_t)mb * 1048576;

  fx4 acc[2][4][4];
#pragma unroll
  for (int q = 0; q < 2; ++q)
#pragma unroll
    for (int a = 0; a < 4; ++a)
#pragma unroll
      for (int b = 0; b < 4; ++b) acc[q][a][b] = (fx4){0.f, 0.f, 0.f, 0.f};

  auto stageA = [&](int buf, int ts, int s) {   // 16 KB = 2 gll16/thread
    char* dst = lds + buf * HLDS + s * 16384;
    const char* src = Asrc + ((size_t)ts * 2 + s) * 16384;
    gll16(src + tid * 16, dst + tid * 16);
    gll16(src + tid * 16 + 8192, dst + tid * 16 + 8192);
  };
  auto stageB = [&](int buf, int ts) {   // main 256 cols: 2 gll16/thread
    char* dstB = lds + buf * HLDS + 32768;
#pragma unroll
    for (int u2 = 0; u2 < 2; ++u2) {
      int u = tid + u2 * 512;
      int kbq = u >> 8, cu = u & 255;
      const char* src = Xbf + ((size_t)(ts * 4 + kbq) * COLP + jb * 256 + cu) * 16;
      gll16(src, dstB + (kbq * 264 + cu) * 16);
    }
    // strip col 256 (4 units), threads 0/128/256/384 via load + ds_write
    if ((tid & 127) == 0) {
      int kbq = tid >> 7;
      uint4 v = *reinterpret_cast<const uint4*>(
          Xbf + ((size_t)(ts * 4 + kbq) * COLP + jb * 256 + 256) * 16);
      *reinterpret_cast<uint4*>(dstB + (kbq * 264 + 256) * 16) = v;
    }
  };

#define READ_A(dst, buf, s, qm)                                                     \
  do {                                                                              \
    const char* Ah_ = lds + (buf) * HLDS + (s) * 16384;                             \
    _Pragma("unroll") for (int mf = 0; mf < 4; ++mf)                                \
      dst[mf] = *(const s16x8*)(Ah_ +                                               \
          (size_t)(kb * 256 + wm * 128 + (qm) * 64 + mf * 16 + ml) * 16);           \
  } while (0)
#define READ_B(dst, buf, off)                                                       \
  do {                                                                              \
    const char* Bh_ = lds + (buf) * HLDS + 32768;                                   \
    _Pragma("unroll") for (int nf = 0; nf < 4; ++nf)                                \
      dst[nf] = *(const s16x8*)(Bh_ +                                               \
          (size_t)(kb * 264 + wn * 64 + nf * 16 + ml + (off)) * 16);                \
  } while (0)
#define MFMA16(acc_, a_, b_)                                                        \
  do {                                                                              \
    __builtin_amdgcn_s_setprio(1);                                                  \
    _Pragma("unroll") for (int mf = 0; mf < 4; ++mf)                                \
      _Pragma("unroll") for (int nf = 0; nf < 4; ++nf)                              \
        acc_[mf][nf] = __builtin_amdgcn_mfma_f32_16x16x32_bf16(                     \
            __builtin_bit_cast(bfx8, a_[mf]), __builtin_bit_cast(bfx8, b_[nf]),     \
            acc_[mf][nf], 0, 0, 0);                                                 \
    __builtin_amdgcn_s_setprio(0);                                                  \
  } while (0)

  s16x8 aA[4], aB[4], bU[4], bV[4];

  // prologue: stage tiles 0,1 into bufs 0,1; drain tile 0 (oldest), keep tile 1
  stageA(0, 0, 0); stageA(0, 0, 1); stageB(0, 0);
  stageA(1, 1, 0); stageA(1, 1, 1); stageB(1, 1);
  asm volatile("s_waitcnt vmcnt(6)" ::: "memory");
  asm volatile("s_waitcnt lgkmcnt(0)" ::: "memory");
  __builtin_amdgcn_s_barrier();

  int bR = 0, bW = 2;
  for (int kt = 0; kt < NKT; ++kt) {
    int ts2 = (kt + 2) & (NKT - 1);
    // s=0 pass: B frags at col+1
    READ_B(bU, bR, 1);
    READ_A(aA, bR, 0, 0);
    stageA(bW, ts2, 0);
    MFMA16(acc[0], aA, bU);
    READ_A(aB, bR, 0, 1);
    stageA(bW, ts2, 1);
    MFMA16(acc[1], aB, bU);
    // s=1 pass: B frags at col
    READ_B(bV, bR, 0);
    READ_A(aA, bR, 1, 0);
    stageB(bW, ts2);
    MFMA16(acc[0], aA, bV);
    READ_A(aB, bR, 1, 1);
    MFMA16(acc[1], aB, bV);
    // drain everything older than this tile's 6 stages -> tile kt+1 ready
    asm volatile("s_waitcnt vmcnt(6)" ::: "memory");
    asm volatile("s_waitcnt lgkmcnt(0)" ::: "memory");
    __builtin_amdgcn_s_barrier();
    bR = (bR == 2) ? 0 : bR + 1;
    bW = (bW == 2) ? 0 : bW + 1;
  }
  asm volatile("s_waitcnt vmcnt(0)" ::: "memory");

  // epilogue: C/D layout col=lane&15, row=(lane>>4)*4+r
  int c0 = jb * 256 + wn * 64;
  int r0 = mb * 256 + wm * 128;
#pragma unroll
  for (int qm = 0; qm < 2; ++qm)
#pragma unroll
    for (int mf = 0; mf < 4; ++mf)
#pragma unroll
      for (int nf = 0; nf < 4; ++nf) {
        int c = c0 + nf * 16 + ml;
        if (c < NOUT) {
          int r = r0 + qm * 64 + mf * 16 + (lane >> 4) * 4;
#pragma unroll
          for (int i = 0; i < 4; ++i)
            Y[(size_t)(r + i) * NOUT + c] = acc[qm][mf][nf][i];
        }
      }
#undef READ_A
#undef READ_B
#undef MFMA16
}

extern "C" void kernel_launch(void* const* d_in, const int* in_sizes, int n_in,
                              void* d_out, int out_size, void* d_ws, size_t ws_size,
                              hipStream_t stream) {
  const float* X     = (const float*)d_in[0];
  const float* A     = (const float*)d_in[1];
  const float* alpha = (const float*)d_in[2];
  const float* beta0 = (const float*)d_in[3];
  const float* beta1 = (const float*)d_in[4];
  float* Y = (float*)d_out;
  char* ws = (char*)d_ws;
  char* Xbf = ws;                       // 34,078,720 B
  char* Apk = ws + APK_OFF;             // 4 MiB
  unsigned* B1 = (unsigned*)(ws + B1_OFF);

  k_masks<<<dim3(1024), dim3(256), 0, stream>>>(A, B1);
  k_wp<<<dim3(9344), dim3(256), 0, stream>>>(B1, alpha, beta0, beta1, X,
                                             (unsigned short*)Apk,
                                             (unsigned short*)Xbf);
  k_gemm<<<dim3(256), dim3(512), 0, stream>>>(Apk, Xbf, Y);
}

// Round 14
// 91.104 us; speedup vs baseline: 1.1031x; 1.0185x over previous
//
#include <hip/hip_runtime.h>

typedef float fx4 __attribute__((ext_vector_type(4)));
typedef short s16x8 __attribute__((ext_vector_type(8)));
typedef __bf16 bfx8 __attribute__((ext_vector_type(8)));

#define KN 1024
#define TT 16384
#define NOUT 16382
#define NKT 32   // K' = 2048, tiles of 64

// ws layout: Bpk (64 MiB) at 0; Apk (4 MiB); B1 bitmasks (128 KiB)
#define APK_OFF 67108864u
#define B1_OFF  (APK_OFF + 4194304u)

__device__ __forceinline__ unsigned short f2bf(float f) {
  return __builtin_bit_cast(unsigned short, (__bf16)f);
}

__device__ __forceinline__ void gll16(const void* g, void* l) {
  __builtin_amdgcn_global_load_lds(
      (const __attribute__((address_space(1))) void*)g,
      (__attribute__((address_space(3))) void*)l, 16, 0, 0);
}

// ---- kernel 1: adjacency bitmask rows (1024 bits = 32 u32 per node) ----
__global__ __launch_bounds__(256) void k_masks(const float* __restrict__ A,
                                               unsigned* __restrict__ B1) {
  int k = blockIdx.x;
  int tid = threadIdx.x;
  int wv = tid >> 6, lane = tid & 63;
  for (int i = 0; i < 4; ++i) {
    int n = i * 256 + wv * 64 + lane;
    bool bit = (A[(size_t)k * KN + n] > 0.5f) && (n != k);
    unsigned long long m = __ballot(bit);
    if (lane == 0) {
      B1[k * 32 + i * 8 + wv * 2]     = (unsigned)m;
      B1[k * 32 + i * 8 + wv * 2 + 1] = (unsigned)(m >> 32);
    }
  }
}

// ---- kernel 2 (fused): blocks 0-1023 build Wc; blocks 1024+ pack X2 ----
__global__ __launch_bounds__(256) void k_wp(const unsigned* __restrict__ B1,
                                            const float* __restrict__ alpha,
                                            const float* __restrict__ beta0,
                                            const float* __restrict__ beta1,
                                            const float* __restrict__ X,
                                            unsigned short* __restrict__ Wc,
                                            unsigned short* __restrict__ Bpk) {
  int tid = threadIdx.x;
  if (blockIdx.x >= 1024) {
    // ---------------- pack path ----------------
    int G = (blockIdx.x - 1024) * 256 + tid;   // 0 .. 4,194,303
    int col = G & 255;
    int kb  = (G >> 8) & 3;
    int qk  = (G >> 10) & 1;
    int kt  = (G >> 11) & 31;
    int jb  = G >> 16;
    int j   = jb * 256 + col;
    int mbase = kt * 32 + qk * 16 + kb * 4;
    unsigned v[4];
#pragma unroll
    for (int p = 0; p < 4; ++p) {
      int m = mbase + p;
      int j1 = j + 1;
      float f0 = (j1 < TT) ? X[(size_t)m * TT + j1] : 0.0f;  // s=0
      float f1 = X[(size_t)m * TT + j];                      // s=1
      v[p] = (unsigned)f2bf(f0) | ((unsigned)f2bf(f1) << 16);
    }
    uint4 w; w.x = v[0]; w.y = v[1]; w.z = v[2]; w.w = v[3];
    *reinterpret_cast<uint4*>(Bpk + (size_t)G * 8) = w;
    return;
  }
  // ---------------- weights path ----------------
  __shared__ unsigned reach[32];
  __shared__ unsigned ex2[32];
  __shared__ unsigned short list[1056];
  __shared__ int nl;
  int k = blockIdx.x;
  if (tid == 0) nl = 0;
  if (tid < 32) {
    unsigned r = B1[k * 32 + tid];
    if (tid == (k >> 5)) r |= 1u << (k & 31);  // reach = {k} | N(k)
    reach[tid] = r;
    ex2[tid] = 0;
  }
  __syncthreads();
  for (int m = tid; m < KN; m += 256)
    if ((reach[m >> 5] >> (m & 31)) & 1) {
      int i = atomicAdd(&nl, 1);
      list[i] = (unsigned short)m;
    }
  __syncthreads();
  int n2 = nl;
  for (int i = 0; i < n2; ++i) {
    int m = list[i];
    if (tid < 32) ex2[tid] |= B1[m * 32 + tid];   // union of N(m), m in reach
  }
  __syncthreads();
  if (tid < 32) ex2[tid] &= ~reach[tid];          // distance exactly 2
  __syncthreads();
  int d1 = 0, d2 = 0;
  for (int w = 0; w < 32; ++w) { d1 += __popc(reach[w]); d2 += __popc(ex2[w]); }
  d1 -= 1;  // remove self bit
  float rd1 = 1.0f / fmaxf((float)d1, 1.0f);
  float rd2 = 1.0f / fmaxf((float)d2, 1.0f);
  float c00 = beta0[0] * rd1, c01 = beta0[1] * rd1;
  float c10 = beta1[0] * rd2, c11 = beta1[1] * rd2;
  float a0 = alpha[0], a1 = alpha[1];
  int mb = k >> 8, rloc = k & 255;
  for (int q = 0; q < 4; ++q) {
    int n = tid * 4 + q;
    bool in1 = (((reach[n >> 5] >> (n & 31)) & 1) != 0) && (n != k);
    bool in2 = ((ex2[n >> 5] >> (n & 31)) & 1) != 0;
    float v0 = (in1 ? c00 : 0.f) + (in2 ? c10 : 0.f) + (n == k ? a0 : 0.f);
    float v1 = (in1 ? c01 : 0.f) + (in2 ? c11 : 0.f) + (n == k ? a1 : 0.f);
    int kt = n >> 5, qk = (n >> 4) & 1, kb = (n >> 2) & 3, ii = (n & 3) * 2;
    size_t idx = ((((size_t)(mb * 32 + kt) * 2 + qk) * 4 + kb) * 256 + rloc) * 8 + ii;
    unsigned pair = (unsigned)f2bf(v0) | ((unsigned)f2bf(v1) << 16);
    *reinterpret_cast<unsigned*>(Wc + idx) = pair;
  }
}

// ---- kernel 3: 256x256 GEMM, one barrier/tile + FLAVOR-SPLIT wave order ----
// Reads from buf kt&1, all 8 stages into buf (kt+1)&1 (disjoint). Waves 0-3
// traverse qk0->qk1; waves 4-7 (their SIMD partners) qk1->qk0 -> while one
// flavor is in its ds_read burst the other is in its MFMA cluster.
__global__ __launch_bounds__(512, 2) void k_gemm(const char* __restrict__ Apk,
                                                 const char* __restrict__ Bpk,
                                                 float* __restrict__ Y) {
  __shared__ char lds[131072];  // 2 buf x { A 32K (h0|h1) | B 32K (h0|h1) }
  int bid = blockIdx.x;
  int swz = (bid & 7) * 32 + (bid >> 3);   // XCD-contiguous work chunks
  int jb = swz >> 2, mb = swz & 3;
  int tid = threadIdx.x;
  int lane = tid & 63, wv = tid >> 6;
  int wm = wv >> 2, wn = wv & 3;           // wave out: rows wm*128, cols wn*64
  int fl = (wv >> 2) & 1;                  // flavor: SIMD-mates wv, wv+4 differ
  int kb = lane >> 4, ml = lane & 15;
  const char* Asrc = Apk + (size_t)mb * (NKT * 2 * 16384);
  const char* Bsrc = Bpk + (size_t)jb * (NKT * 2 * 16384);

  fx4 acc[2][4][4];
#pragma unroll
  for (int q = 0; q < 2; ++q)
#pragma unroll
    for (int a = 0; a < 4; ++a)
#pragma unroll
      for (int b = 0; b < 4; ++b) acc[q][a][b] = (fx4){0.f, 0.f, 0.f, 0.f};

  auto stage_half = [&](int tile, int isB, int qh) {
    char* dst = lds + (tile & 1) * 65536 + isB * 32768 + qh * 16384;
    const char* src = (isB ? Bsrc : Asrc) + ((size_t)(tile & (NKT - 1)) * 2 + qh) * 16384;
    gll16(src + tid * 16, dst + tid * 16);
    gll16(src + (size_t)(tid + 512) * 16, dst + (tid + 512) * 16);
  };

#define READ_A(dst, t, qk, qm)                                                      \
  do {                                                                              \
    const char* Ah_ = lds + ((t) & 1) * 65536 + (qk) * 16384;                       \
    _Pragma("unroll") for (int mf = 0; mf < 4; ++mf)                                \
      dst[mf] = *(const s16x8*)(Ah_ +                                               \
          (size_t)(kb * 256 + wm * 128 + (qm) * 64 + mf * 16 + ml) * 16);           \
  } while (0)
#define READ_B(dst, t, qk)                                                          \
  do {                                                                              \
    const char* Bh_ = lds + ((t) & 1) * 65536 + 32768 + (qk) * 16384;               \
    _Pragma("unroll") for (int nf = 0; nf < 4; ++nf)                                \
      dst[nf] = *(const s16x8*)(Bh_ +                                               \
          (size_t)(kb * 256 + wn * 64 + nf * 16 + ml) * 16);                        \
  } while (0)
#define MFMA16(acc_, a_, b_)                                                        \
  do {                                                                              \
    __builtin_amdgcn_s_setprio(1);                                                  \
    _Pragma("unroll") for (int mf = 0; mf < 4; ++mf)                                \
      _Pragma("unroll") for (int nf = 0; nf < 4; ++nf)                              \
        acc_[mf][nf] = __builtin_amdgcn_mfma_f32_16x16x32_bf16(                     \
            __builtin_bit_cast(bfx8, a_[mf]), __builtin_bit_cast(bfx8, b_[nf]),     \
            acc_[mf][nf], 0, 0, 0);                                                 \
    __builtin_amdgcn_s_setprio(0);                                                  \
  } while (0)

// one qk pass: reads + 2 MFMA clusters + (optionally) this flavor's stages
#define QK_PASS(qk, DO_STAGE)                                                       \
  do {                                                                              \
    READ_B(bA, kt, qk);                                                             \
    READ_A(aA, kt, qk, 0);                                                          \
    if (DO_STAGE) { stage_half(kt + 1, 0, 0); stage_half(kt + 1, 1, 0); }           \
    MFMA16(acc[0], aA, bA);                                                         \
    READ_A(aB, kt, qk, 1);                                                          \
    if (DO_STAGE) { stage_half(kt + 1, 0, 1); stage_half(kt + 1, 1, 1); }           \
    MFMA16(acc[1], aB, bA);                                                         \
  } while (0)

  s16x8 aA[4], aB[4], bA[4];

  // prologue: stage all 4 halves of tile 0; full drain; barrier
  stage_half(0, 0, 0); stage_half(0, 1, 0);
  stage_half(0, 0, 1); stage_half(0, 1, 1);
  asm volatile("s_waitcnt vmcnt(0)" ::: "memory");
  __builtin_amdgcn_s_barrier();

  for (int kt = 0; kt < NKT; ++kt) {
    if (fl == 0) {
      QK_PASS(0, 1);   // stages issued in first pass (early)
      QK_PASS(1, 0);
    } else {
      QK_PASS(1, 1);
      QK_PASS(0, 0);
    }
    asm volatile("s_waitcnt vmcnt(0)" ::: "memory");  // exactly the 8 stages
    __builtin_amdgcn_s_barrier();
  }

  // epilogue: C/D layout col=lane&15, row=(lane>>4)*4+r
  int c0 = jb * 256 + wn * 64;
  int r0 = mb * 256 + wm * 128;
#pragma unroll
  for (int qm = 0; qm < 2; ++qm)
#pragma unroll
    for (int mf = 0; mf < 4; ++mf)
#pragma unroll
      for (int nf = 0; nf < 4; ++nf) {
        int c = c0 + nf * 16 + ml;
        if (c < NOUT) {
          int r = r0 + qm * 64 + mf * 16 + (lane >> 4) * 4;
#pragma unroll
          for (int i = 0; i < 4; ++i)
            Y[(size_t)(r + i) * NOUT + c] = acc[qm][mf][nf][i];
        }
      }
#undef READ_A
#undef READ_B
#undef MFMA16
#undef QK_PASS
}

extern "C" void kernel_launch(void* const* d_in, const int* in_sizes, int n_in,
                              void* d_out, int out_size, void* d_ws, size_t ws_size,
                              hipStream_t stream) {
  const float* X     = (const float*)d_in[0];
  const float* A     = (const float*)d_in[1];
  const float* alpha = (const float*)d_in[2];
  const float* beta0 = (const float*)d_in[3];
  const float* beta1 = (const float*)d_in[4];
  float* Y = (float*)d_out;
  char* ws = (char*)d_ws;
  char* Bpk = ws;                       // 64 MiB
  char* Apk = ws + APK_OFF;             // 4 MiB
  unsigned* B1 = (unsigned*)(ws + B1_OFF);

  k_masks<<<dim3(1024), dim3(256), 0, stream>>>(A, B1);
  k_wp<<<dim3(17408), dim3(256), 0, stream>>>(B1, alpha, beta0, beta1, X,
                                              (unsigned short*)Apk,
                                              (unsigned short*)Bpk);
  k_gemm<<<dim3(256), dim3(512), 0, stream>>>(Apk, Bpk, Y);
}

// Round 15
// 83.965 us; speedup vs baseline: 1.1969x; 1.0850x over previous
//
#include <hip/hip_runtime.h>

typedef float fx4 __attribute__((ext_vector_type(4)));
typedef short s16x8 __attribute__((ext_vector_type(8)));
typedef __bf16 bfx8 __attribute__((ext_vector_type(8)));

#define KN 1024
#define TT 16384
#define NOUT 16382
#define NKT 32      // 32 tiles; tile = {s=0,s=1} x 32 m-rows = 64 k'
#define COLP 16640  // padded X^T cols (65 x 256)
#define HLDS 49216  // per-buffer LDS: A 32768 + B 16384 + seam 64

// ws: Xbf (34,078,720 B) at 0; Apk (4 MiB); B1 bitmasks
#define APK_OFF 34078720u
#define B1_OFF  (APK_OFF + 4194304u)

__device__ __forceinline__ unsigned short f2bf(float f) {
  return __builtin_bit_cast(unsigned short, (__bf16)f);
}

__device__ __forceinline__ void gll16(const void* g, void* l) {
  __builtin_amdgcn_global_load_lds(
      (const __attribute__((address_space(1))) void*)g,
      (__attribute__((address_space(3))) void*)l, 16, 0, 0);
}

// ---- kernel 1: adjacency bitmask rows ----
__global__ __launch_bounds__(256) void k_masks(const float* __restrict__ A,
                                               unsigned* __restrict__ B1) {
  int k = blockIdx.x;
  int tid = threadIdx.x;
  int wv = tid >> 6, lane = tid & 63;
  for (int i = 0; i < 4; ++i) {
    int n = i * 256 + wv * 64 + lane;
    bool bit = (A[(size_t)k * KN + n] > 0.5f) && (n != k);
    unsigned long long m = __ballot(bit);
    if (lane == 0) {
      B1[k * 32 + i * 8 + wv * 2]     = (unsigned)m;
      B1[k * 32 + i * 8 + wv * 2 + 1] = (unsigned)(m >> 32);
    }
  }
}

// ---- kernel 2 (fused): blocks 0-1023 build Wc (s-stacked); 1024+ pack X^T ----
// Wc u16 idx = mb*524288 + t*16384 + s*8192 + kb*2048 + rloc*8 + ii
//   (A for tile t half s: W_s[row = mb*256+rloc, n = t*32 + kb*8 + ii])
// Xbf unit (o,c): 16 B = 8 bf16 = X[o*8+i, c] (0 for c >= 16384), o 0..127, c 0..16639
__global__ __launch_bounds__(256) void k_wp(const unsigned* __restrict__ B1,
                                            const float* __restrict__ alpha,
                                            const float* __restrict__ beta0,
                                            const float* __restrict__ beta1,
                                            const float* __restrict__ X,
                                            unsigned short* __restrict__ Wc,
                                            unsigned short* __restrict__ Xbf) {
  int tid = threadIdx.x;
  if (blockIdx.x >= 1024) {
    // ---------------- pack path: plain bf16 X^T, octet-major ----------------
    int p = blockIdx.x - 1024;       // 0..8319
    int o = p & 127;                 // m-octet
    int cb = p >> 7;                 // 0..64
    int c = cb * 256 + tid;          // 0..16639
    unsigned v[4];
#pragma unroll
    for (int q = 0; q < 4; ++q) {
      float f0 = 0.f, f1 = 0.f;
      if (c < TT) {
        f0 = X[(size_t)(o * 8 + q * 2) * TT + c];
        f1 = X[(size_t)(o * 8 + q * 2 + 1) * TT + c];
      }
      v[q] = (unsigned)f2bf(f0) | ((unsigned)f2bf(f1) << 16);
    }
    uint4 w; w.x = v[0]; w.y = v[1]; w.z = v[2]; w.w = v[3];
    *reinterpret_cast<uint4*>(Xbf + ((size_t)o * COLP + c) * 8) = w;
    return;
  }
  // ---------------- weights path ----------------
  __shared__ unsigned reach[32];
  __shared__ unsigned ex2[32];
  __shared__ unsigned short list[1056];
  __shared__ int nl;
  int k = blockIdx.x;
  if (tid == 0) nl = 0;
  if (tid < 32) {
    unsigned r = B1[k * 32 + tid];
    if (tid == (k >> 5)) r |= 1u << (k & 31);  // reach = {k} | N(k)
    reach[tid] = r;
    ex2[tid] = 0;
  }
  __syncthreads();
  for (int m = tid; m < KN; m += 256)
    if ((reach[m >> 5] >> (m & 31)) & 1) {
      int i = atomicAdd(&nl, 1);
      list[i] = (unsigned short)m;
    }
  __syncthreads();
  int n2 = nl;
  for (int i = 0; i < n2; ++i) {
    int m = list[i];
    if (tid < 32) ex2[tid] |= B1[m * 32 + tid];
  }
  __syncthreads();
  if (tid < 32) ex2[tid] &= ~reach[tid];          // distance exactly 2
  __syncthreads();
  int d1 = 0, d2 = 0;
  for (int w = 0; w < 32; ++w) { d1 += __popc(reach[w]); d2 += __popc(ex2[w]); }
  d1 -= 1;
  float rd1 = 1.0f / fmaxf((float)d1, 1.0f);
  float rd2 = 1.0f / fmaxf((float)d2, 1.0f);
  float c00 = beta0[0] * rd1, c01 = beta0[1] * rd1;
  float c10 = beta1[0] * rd2, c11 = beta1[1] * rd2;
  float a0 = alpha[0], a1 = alpha[1];
  int mb = k >> 8, rloc = k & 255;
  for (int q = 0; q < 4; ++q) {
    int n = tid * 4 + q;
    bool in1 = (((reach[n >> 5] >> (n & 31)) & 1) != 0) && (n != k);
    bool in2 = ((ex2[n >> 5] >> (n & 31)) & 1) != 0;
    float v0 = (in1 ? c00 : 0.f) + (in2 ? c10 : 0.f) + (n == k ? a0 : 0.f);
    float v1 = (in1 ? c01 : 0.f) + (in2 ? c11 : 0.f) + (n == k ? a1 : 0.f);
    int t = n >> 5, kb2 = (n >> 3) & 3, ii = n & 7;
    size_t base = (size_t)mb * 524288 + (size_t)t * 16384 +
                  kb2 * 2048 + rloc * 8 + ii;
    Wc[base] = f2bf(v0);            // s = 0 (pairs with X[., j+1])
    Wc[base + 8192] = f2bf(v1);     // s = 1 (pairs with X[., j])
  }
}

// ---- kernel 3: 256x256 GEMM, s-major shared-B, R14 skeleton ----
// Tile = 32 m-rows x {s0,s1}. B staged ONCE per tile ([kb][256] + 4-unit seam);
// s=0 frags read cols+1 (seam for c==256), s=1 read cols. One vmcnt(0)+barrier
// per tile; reads from buf kt&1, stages into buf (kt+1)&1; flavor-split order.
__global__ __launch_bounds__(512, 2) void k_gemm(const char* __restrict__ Apk,
                                                 const char* __restrict__ Xbf,
                                                 float* __restrict__ Y) {
  __shared__ __align__(16) char lds[2 * HLDS];
  int bid = blockIdx.x;
  int swz = (bid & 7) * 32 + (bid >> 3);   // XCD-contiguous work chunks
  int jb = swz >> 2, mb = swz & 3;
  int tid = threadIdx.x;
  int lane = tid & 63, wv = tid >> 6;
  int wm = wv >> 2, wn = wv & 3;           // wave out: rows wm*128, cols wn*64
  int fl = (wv >> 2) & 1;                  // flavor: SIMD-mates differ
  int kb = lane >> 4, ml = lane & 15;
  const char* Asrc = Apk + (size_t)mb * 1048576;

  fx4 acc[2][4][4];
#pragma unroll
  for (int q = 0; q < 2; ++q)
#pragma unroll
    for (int a = 0; a < 4; ++a)
#pragma unroll
      for (int b = 0; b < 4; ++b) acc[q][a][b] = (fx4){0.f, 0.f, 0.f, 0.f};

  auto stageA = [&](int t) {   // 32 KB: 4 gll16/thread
    char* dst = lds + (t & 1) * HLDS;
    const char* src = Asrc + (size_t)(t & (NKT - 1)) * 32768;
#pragma unroll
    for (int u = 0; u < 4; ++u)
      gll16(src + tid * 16 + u * 8192, dst + tid * 16 + u * 8192);
  };
  auto stageB = [&](int t) {   // 16 KB main + seam
    char* dstB = lds + (t & 1) * HLDS + 32768;
    int ts = t & (NKT - 1);
#pragma unroll
    for (int u2 = 0; u2 < 2; ++u2) {
      int u = tid + u2 * 512;
      const char* src = Xbf +
          ((size_t)(ts * 4 + (u >> 8)) * COLP + jb * 256 + (u & 255)) * 16;
      gll16(src, dstB + u * 16);
    }
    if (tid < 4) {   // seam col 256, units [kb]; lanes 0-3 -> dst+lane*16
      const char* src = Xbf +
          ((size_t)(ts * 4 + tid) * COLP + jb * 256 + 256) * 16;
      gll16(src, dstB + 16384);
    }
  };

#define READ_A(dst, t, s, qm)                                                       \
  do {                                                                              \
    const char* Ah_ = lds + ((t) & 1) * HLDS + (s) * 16384;                         \
    _Pragma("unroll") for (int mf = 0; mf < 4; ++mf)                                \
      dst[mf] = *(const s16x8*)(Ah_ +                                               \
          (size_t)(kb * 256 + wm * 128 + (qm) * 64 + mf * 16 + ml) * 16);           \
  } while (0)
#define READ_B(dst, t, off)                                                         \
  do {                                                                              \
    const char* Bh_ = lds + ((t) & 1) * HLDS + 32768;                               \
    _Pragma("unroll") for (int nf = 0; nf < 4; ++nf) {                              \
      int c_ = wn * 64 + nf * 16 + ml + (off);                                      \
      const char* a_ = Bh_ + (size_t)(kb * 256 + c_) * 16;                          \
      if ((off) == 1 && nf == 3) {                                                  \
        if (c_ == 256) a_ = Bh_ + 16384 + kb * 16;                                  \
      }                                                                             \
      dst[nf] = *(const s16x8*)a_;                                                  \
    }                                                                               \
  } while (0)
#define MFMA16(acc_, a_, b_)                                                        \
  do {                                                                              \
    __builtin_amdgcn_s_setprio(1);                                                  \
    _Pragma("unroll") for (int mf = 0; mf < 4; ++mf)                                \
      _Pragma("unroll") for (int nf = 0; nf < 4; ++nf)                              \
        acc_[mf][nf] = __builtin_amdgcn_mfma_f32_16x16x32_bf16(                     \
            __builtin_bit_cast(bfx8, a_[mf]), __builtin_bit_cast(bfx8, b_[nf]),     \
            acc_[mf][nf], 0, 0, 0);                                                 \
    __builtin_amdgcn_s_setprio(0);                                                  \
  } while (0)

// one s pass: B frags at cols + (1-s); optional stage of tile kt+1
#define S_PASS(s, DO_STAGE)                                                         \
  do {                                                                              \
    READ_B(bA, kt, 1 - (s));                                                        \
    READ_A(aA, kt, s, 0);                                                           \
    if (DO_STAGE) stageA(kt + 1);                                                   \
    MFMA16(acc[0], aA, bA);                                                         \
    READ_A(aB, kt, s, 1);                                                           \
    if (DO_STAGE) stageB(kt + 1);                                                   \
    MFMA16(acc[1], aB, bA);                                                         \
  } while (0)

  s16x8 aA[4], aB[4], bA[4];

  // prologue: stage tile 0; full drain; barrier
  stageA(0); stageB(0);
  asm volatile("s_waitcnt vmcnt(0)" ::: "memory");
  __builtin_amdgcn_s_barrier();

  for (int kt = 0; kt < NKT; ++kt) {
    if (fl == 0) {
      S_PASS(0, 1);   // stage during first pass (early issue)
      S_PASS(1, 0);
    } else {
      S_PASS(1, 1);
      S_PASS(0, 0);
    }
    asm volatile("s_waitcnt vmcnt(0)" ::: "memory");
    __builtin_amdgcn_s_barrier();
  }

  // epilogue: C/D layout col=lane&15, row=(lane>>4)*4+r
  int c0 = jb * 256 + wn * 64;
  int r0 = mb * 256 + wm * 128;
#pragma unroll
  for (int qm = 0; qm < 2; ++qm)
#pragma unroll
    for (int mf = 0; mf < 4; ++mf)
#pragma unroll
      for (int nf = 0; nf < 4; ++nf) {
        int c = c0 + nf * 16 + ml;
        if (c < NOUT) {
          int r = r0 + qm * 64 + mf * 16 + (lane >> 4) * 4;
#pragma unroll
          for (int i = 0; i < 4; ++i)
            Y[(size_t)(r + i) * NOUT + c] = acc[qm][mf][nf][i];
        }
      }
#undef READ_A
#undef READ_B
#undef MFMA16
#undef S_PASS
}

extern "C" void kernel_launch(void* const* d_in, const int* in_sizes, int n_in,
                              void* d_out, int out_size, void* d_ws, size_t ws_size,
                              hipStream_t stream) {
  const float* X     = (const float*)d_in[0];
  const float* A     = (const float*)d_in[1];
  const float* alpha = (const float*)d_in[2];
  const float* beta0 = (const float*)d_in[3];
  const float* beta1 = (const float*)d_in[4];
  float* Y = (float*)d_out;
  char* ws = (char*)d_ws;
  char* Xbf = ws;                       // 34,078,720 B
  char* Apk = ws + APK_OFF;             // 4 MiB
  unsigned* B1 = (unsigned*)(ws + B1_OFF);

  k_masks<<<dim3(1024), dim3(256), 0, stream>>>(A, B1);
  k_wp<<<dim3(9344), dim3(256), 0, stream>>>(B1, alpha, beta0, beta1, X,
                                             (unsigned short*)Apk,
                                             (unsigned short*)Xbf);
  k_gemm<<<dim3(256), dim3(512), 0, stream>>>(Apk, Xbf, Y);
}

// Round 16
// 81.375 us; speedup vs baseline: 1.2350x; 1.0318x over previous
//
#include <hip/hip_runtime.h>

typedef float fx4 __attribute__((ext_vector_type(4)));
typedef short s16x8 __attribute__((ext_vector_type(8)));
typedef __bf16 bfx8 __attribute__((ext_vector_type(8)));

#define KN 1024
#define TT 16384
#define NOUT 16382
#define NKT 32      // 32 tiles; tile = {s=0,s=1} x 32 m-rows = 64 k'
#define COLP 16640  // padded X^T cols (65 x 256)
#define HLDS 32832  // per-buffer LDS: A 16384 + B 16384 + seam 64

// ws: Xbf (34,078,720 B) at 0; Apk (4 MiB); B1 bitmasks
#define APK_OFF 34078720u
#define B1_OFF  (APK_OFF + 4194304u)

__device__ __forceinline__ unsigned short f2bf(float f) {
  return __builtin_bit_cast(unsigned short, (__bf16)f);
}

__device__ __forceinline__ void gll16(const void* g, void* l) {
  __builtin_amdgcn_global_load_lds(
      (const __attribute__((address_space(1))) void*)g,
      (__attribute__((address_space(3))) void*)l, 16, 0, 0);
}

// ---- kernel 1: adjacency bitmask rows ----
__global__ __launch_bounds__(256) void k_masks(const float* __restrict__ A,
                                               unsigned* __restrict__ B1) {
  int k = blockIdx.x;
  int tid = threadIdx.x;
  int wv = tid >> 6, lane = tid & 63;
  for (int i = 0; i < 4; ++i) {
    int n = i * 256 + wv * 64 + lane;
    bool bit = (A[(size_t)k * KN + n] > 0.5f) && (n != k);
    unsigned long long m = __ballot(bit);
    if (lane == 0) {
      B1[k * 32 + i * 8 + wv * 2]     = (unsigned)m;
      B1[k * 32 + i * 8 + wv * 2 + 1] = (unsigned)(m >> 32);
    }
  }
}

// ---- kernel 2 (fused): blocks 0-1023 build Wc (s-stacked); 1024+ pack X^T ----
// Wc u16 idx = mb*524288 + t*16384 + s*8192 + kb*2048 + rloc*8 + ii  (mb 0..3, rloc 0..255)
// Xbf unit (o,c): 16 B = 8 bf16 = X[o*8+i, c] (0 for c >= 16384)
__global__ __launch_bounds__(256) void k_wp(const unsigned* __restrict__ B1,
                                            const float* __restrict__ alpha,
                                            const float* __restrict__ beta0,
                                            const float* __restrict__ beta1,
                                            const float* __restrict__ X,
                                            unsigned short* __restrict__ Wc,
                                            unsigned short* __restrict__ Xbf) {
  int tid = threadIdx.x;
  if (blockIdx.x >= 1024) {
    // ---------------- pack path: plain bf16 X^T, octet-major ----------------
    int p = blockIdx.x - 1024;       // 0..8319
    int o = p & 127;                 // m-octet
    int cb = p >> 7;                 // 0..64
    int c = cb * 256 + tid;          // 0..16639
    unsigned v[4];
#pragma unroll
    for (int q = 0; q < 4; ++q) {
      float f0 = 0.f, f1 = 0.f;
      if (c < TT) {
        f0 = X[(size_t)(o * 8 + q * 2) * TT + c];
        f1 = X[(size_t)(o * 8 + q * 2 + 1) * TT + c];
      }
      v[q] = (unsigned)f2bf(f0) | ((unsigned)f2bf(f1) << 16);
    }
    uint4 w; w.x = v[0]; w.y = v[1]; w.z = v[2]; w.w = v[3];
    *reinterpret_cast<uint4*>(Xbf + ((size_t)o * COLP + c) * 8) = w;
    return;
  }
  // ---------------- weights path ----------------
  __shared__ unsigned reach[32];
  __shared__ unsigned ex2[32];
  __shared__ unsigned short list[1056];
  __shared__ int nl;
  int k = blockIdx.x;
  if (tid == 0) nl = 0;
  if (tid < 32) {
    unsigned r = B1[k * 32 + tid];
    if (tid == (k >> 5)) r |= 1u << (k & 31);  // reach = {k} | N(k)
    reach[tid] = r;
    ex2[tid] = 0;
  }
  __syncthreads();
  for (int m = tid; m < KN; m += 256)
    if ((reach[m >> 5] >> (m & 31)) & 1) {
      int i = atomicAdd(&nl, 1);
      list[i] = (unsigned short)m;
    }
  __syncthreads();
  int n2 = nl;
  for (int i = 0; i < n2; ++i) {
    int m = list[i];
    if (tid < 32) ex2[tid] |= B1[m * 32 + tid];
  }
  __syncthreads();
  if (tid < 32) ex2[tid] &= ~reach[tid];          // distance exactly 2
  __syncthreads();
  int d1 = 0, d2 = 0;
  for (int w = 0; w < 32; ++w) { d1 += __popc(reach[w]); d2 += __popc(ex2[w]); }
  d1 -= 1;
  float rd1 = 1.0f / fmaxf((float)d1, 1.0f);
  float rd2 = 1.0f / fmaxf((float)d2, 1.0f);
  float c00 = beta0[0] * rd1, c01 = beta0[1] * rd1;
  float c10 = beta1[0] * rd2, c11 = beta1[1] * rd2;
  float a0 = alpha[0], a1 = alpha[1];
  int mb = k >> 8, rloc = k & 255;
  for (int q = 0; q < 4; ++q) {
    int n = tid * 4 + q;
    bool in1 = (((reach[n >> 5] >> (n & 31)) & 1) != 0) && (n != k);
    bool in2 = ((ex2[n >> 5] >> (n & 31)) & 1) != 0;
    float v0 = (in1 ? c00 : 0.f) + (in2 ? c10 : 0.f) + (n == k ? a0 : 0.f);
    float v1 = (in1 ? c01 : 0.f) + (in2 ? c11 : 0.f) + (n == k ? a1 : 0.f);
    int t = n >> 5, kb2 = (n >> 3) & 3, ii = n & 7;
    size_t base = (size_t)mb * 524288 + (size_t)t * 16384 +
                  kb2 * 2048 + rloc * 8 + ii;
    Wc[base] = f2bf(v0);            // s = 0 (pairs with X[., j+1])
    Wc[base + 8192] = f2bf(v1);     // s = 1 (pairs with X[., j])
  }
}

// ---- kernel 3: 128x256-tile GEMM, 2 blocks/CU (independent barrier domains) ----
// 256 thr, 4 waves (2M x 2N), wave tile 64x128. B staged once/tile (s-shared);
// s=0 reads cols+1 (seam at c==256), s=1 cols. One vmcnt(0)+barrier per tile;
// reads from buf kt&1, stages into buf (kt+1)&1.
__global__ __launch_bounds__(256, 2) void k_gemm(const char* __restrict__ Apk,
                                                 const char* __restrict__ Xbf,
                                                 float* __restrict__ Y) {
  __shared__ __align__(16) char lds[2 * HLDS];
  int bid = blockIdx.x;
  int swz = (bid & 7) * 64 + (bid >> 3);   // XCD-contiguous (512 % 8 == 0)
  int jb = swz >> 3, mb = swz & 7;         // jb 0..63, mb 0..7 (128-row slices)
  int mb4 = mb >> 1, half = mb & 1;
  int tid = threadIdx.x;
  int lane = tid & 63, wv = tid >> 6;
  int wm = wv >> 1, wn = wv & 1;           // wave tile: rows wm*64, cols wn*128
  int kb = lane >> 4, ml = lane & 15;
  const char* Asrc = Apk + (size_t)mb4 * 524288 * 2;  // byte base of mb4 slice

  fx4 acc[4][8];
#pragma unroll
  for (int a = 0; a < 4; ++a)
#pragma unroll
    for (int b = 0; b < 8; ++b) acc[a][b] = (fx4){0.f, 0.f, 0.f, 0.f};

  auto stageA = [&](int t) {   // 16 KB (both s halves of this block's 128 rows)
    char* dst = lds + (t & 1) * HLDS;
    int ts = t & (NKT - 1);
    // u = s*512 + kb*128 + r ; src byte = ts*32768 + s*16384 + kb*4096 + (half*128+r)*16
#pragma unroll
    for (int q = 0; q < 4; ++q) {
      int u = tid + q * 256;
      int s_ = u >> 9, kb_ = (u >> 7) & 3, r_ = u & 127;
      const char* src = Asrc + (size_t)ts * 32768 + s_ * 16384 + kb_ * 4096 +
                        (half * 128 + r_) * 16;
      gll16(src, dst + u * 16);
    }
  };
  auto stageB = [&](int t) {   // 16 KB main + seam
    char* dstB = lds + (t & 1) * HLDS + 16384;
    int ts = t & (NKT - 1);
#pragma unroll
    for (int u2 = 0; u2 < 4; ++u2) {
      int u = tid + u2 * 256;
      const char* src = Xbf +
          ((size_t)(ts * 4 + (u >> 8)) * COLP + jb * 256 + (u & 255)) * 16;
      gll16(src, dstB + u * 16);
    }
    if (tid < 4) {   // seam col 256; lanes 0-3 land at dst+lane*16
      const char* src = Xbf +
          ((size_t)(ts * 4 + tid) * COLP + jb * 256 + 256) * 16;
      gll16(src, dstB + 16384);
    }
  };

#define READ_A(dst, t, s)                                                           \
  do {                                                                              \
    const char* Ah_ = lds + ((t) & 1) * HLDS + (s) * 8192;                          \
    _Pragma("unroll") for (int mf = 0; mf < 4; ++mf)                                \
      dst[mf] = *(const s16x8*)(Ah_ +                                               \
          (size_t)(kb * 128 + wm * 64 + mf * 16 + ml) * 16);                        \
  } while (0)
#define READ_B(dst, t, off)                                                         \
  do {                                                                              \
    const char* Bh_ = lds + ((t) & 1) * HLDS + 16384;                               \
    _Pragma("unroll") for (int nf = 0; nf < 8; ++nf) {                              \
      int c_ = wn * 128 + nf * 16 + ml + (off);                                     \
      const char* a_ = Bh_ + (size_t)(kb * 256 + c_) * 16;                          \
      if ((off) == 1 && nf == 7) {                                                  \
        if (c_ == 256) a_ = Bh_ + 16384 + kb * 16;                                  \
      }                                                                             \
      dst[nf] = *(const s16x8*)a_;                                                  \
    }                                                                               \
  } while (0)
#define MFMA32(a_, b_)                                                              \
  do {                                                                              \
    __builtin_amdgcn_s_setprio(1);                                                  \
    _Pragma("unroll") for (int mf = 0; mf < 4; ++mf)                                \
      _Pragma("unroll") for (int nf = 0; nf < 8; ++nf)                              \
        acc[mf][nf] = __builtin_amdgcn_mfma_f32_16x16x32_bf16(                      \
            __builtin_bit_cast(bfx8, a_[mf]), __builtin_bit_cast(bfx8, b_[nf]),     \
            acc[mf][nf], 0, 0, 0);                                                  \
    __builtin_amdgcn_s_setprio(0);                                                  \
  } while (0)

  s16x8 aA[4], bA[8];

  // prologue: stage tile 0; full drain; barrier
  stageA(0); stageB(0);
  asm volatile("s_waitcnt vmcnt(0)" ::: "memory");
  __builtin_amdgcn_s_barrier();

  for (int kt = 0; kt < NKT; ++kt) {
    // s=0 pass (B at cols+1); stage A(kt+1) early
    READ_B(bA, kt, 1);
    READ_A(aA, kt, 0);
    stageA(kt + 1);
    MFMA32(aA, bA);
    // s=1 pass (B at cols); stage B(kt+1)
    READ_B(bA, kt, 0);
    READ_A(aA, kt, 1);
    stageB(kt + 1);
    MFMA32(aA, bA);
    asm volatile("s_waitcnt vmcnt(0)" ::: "memory");
    __builtin_amdgcn_s_barrier();
  }

  // epilogue: C/D layout col=lane&15, row=(lane>>4)*4+r
  int c0 = jb * 256 + wn * 128;
  int r0 = mb * 128 + wm * 64;
#pragma unroll
  for (int mf = 0; mf < 4; ++mf)
#pragma unroll
    for (int nf = 0; nf < 8; ++nf) {
      int c = c0 + nf * 16 + ml;
      if (c < NOUT) {
        int r = r0 + mf * 16 + (lane >> 4) * 4;
#pragma unroll
        for (int i = 0; i < 4; ++i)
          Y[(size_t)(r + i) * NOUT + c] = acc[mf][nf][i];
      }
    }
#undef READ_A
#undef READ_B
#undef MFMA32
}

extern "C" void kernel_launch(void* const* d_in, const int* in_sizes, int n_in,
                              void* d_out, int out_size, void* d_ws, size_t ws_size,
                              hipStream_t stream) {
  const float* X     = (const float*)d_in[0];
  const float* A     = (const float*)d_in[1];
  const float* alpha = (const float*)d_in[2];
  const float* beta0 = (const float*)d_in[3];
  const float* beta1 = (const float*)d_in[4];
  float* Y = (float*)d_out;
  char* ws = (char*)d_ws;
  char* Xbf = ws;                       // 34,078,720 B
  char* Apk = ws + APK_OFF;             // 4 MiB
  unsigned* B1 = (unsigned*)(ws + B1_OFF);

  k_masks<<<dim3(1024), dim3(256), 0, stream>>>(A, B1);
  k_wp<<<dim3(9344), dim3(256), 0, stream>>>(B1, alpha, beta0, beta1, X,
                                             (unsigned short*)Apk,
                                             (unsigned short*)Xbf);
  k_gemm<<<dim3(512), dim3(256), 0, stream>>>(Apk, Xbf, Y);
}